// Round 1
// baseline (26.582 us; speedup 1.0000x reference)
//
#include <hip/hip_runtime.h>

// CenterLoss — R9: R8's structure; ONE theory applied: overlap the per-row
// serial tail with the next row's streaming loads.
//   (a) features[n] load hoisted into Phase A (independent of argmax) so its
//       HBM latency hides under the 7 predict loads, not in the wave-0 tail.
//   (b) third per-row __syncthreads removed; dist section moved after the
//       sFi read. Safety: row r's sMax reads precede barrier B(r); row r+1's
//       sMax writes follow it. Row r's sFi reads precede barrier A(r+1);
//       row r+1's sFi writes follow it. Two barriers/row are sufficient.
//       Waves 1-3 run ahead into row r+1 Phase A while wave 0 gathers
//       centers[lab] + stores — 3/4 of the block's streaming restarts at once.
// Kept from R5..R8 (measured): 2048 blocks x 2 rows (all 32 waves/CU resident,
// one generation); #pragma unroll 1 (no cross-row load hoist / VGPR bloat);
// two-kernel store-and-reduce (same-address atomics +45 us, acq-rel +165 us).
//
// loss = mean_n( clip(||f||^2 + ||c_lab||^2 - 2 f.c_lab, 1e-12, 1e12) ) + (C-1)*1e-12
// lab = argmax_c predicts[n, c]  (first occurrence on ties).

#define NC   6625
#define FD   96
#define NROW 4096
#define RPB  2      // rows per block

__global__ __launch_bounds__(256) void centerloss_row_kernel(
    const float* __restrict__ features,
    const float* __restrict__ predicts,
    const float* __restrict__ centers,
    float* __restrict__ row_out)
{
    const int t = threadIdx.x;
    const float NEG_INF = -__builtin_huge_valf();

    __shared__ float sMax[4];
    __shared__ int   sFi[4];

    #pragma unroll 1
    for (int r = 0; r < RPB; ++r) {
        const int n = blockIdx.x * RPB + r;
        const size_t base = (size_t)n * NC;
        const float* row = predicts + base;

        // Row start is only 4B-aligned (6625 % 4 == 1): scalar prologue to 16B.
        const int pro  = (int)((4 - (base & 3)) & 3);     // 0..3
        const int nvec = (NC - pro) >> 2;                 // 1655 or 1656
        const float4* vrow = (const float4*)(row + pro);

        // ---- Phase A: issue all loads, values live in named registers ----
        // Chunks 0..5 unconditional: max index 255+1280=1535 < min nvec=1655.
        const float4 v0 = vrow[t];
        const float4 v1 = vrow[t +  256];
        const float4 v2 = vrow[t +  512];
        const float4 v3 = vrow[t +  768];
        const float4 v4 = vrow[t + 1024];
        const float4 v5 = vrow[t + 1280];
        float4 v6 = make_float4(NEG_INF, NEG_INF, NEG_INF, NEG_INF);
        const int i6 = t + 1536;
        if (i6 < nvec) v6 = vrow[i6];                     // ~120 lanes valid

        float vpro = NEG_INF;
        if (t < pro) vpro = row[t];                       // idx = t
        const int tailStart = pro + 4 * nvec;
        float vtail = NEG_INF;
        if (t < NC - tailStart) vtail = row[tailStart + t];

        // features[n] is argmax-independent: issue it with the streaming burst
        // so its HBM latency is hidden here, not in the wave-0 dist tail.
        float4 f = make_float4(0.f, 0.f, 0.f, 0.f);
        if (t < 24)                                        // 24 * float4 = 96
            f = ((const float4*)(features + (size_t)n * FD))[t];

        // Thread max via fmax tree (fuses to v_max3_f32); no index tracking.
        float m = fmaxf(fmaxf(fmaxf(v0.x, v0.y), fmaxf(v0.z, v0.w)),
                        fmaxf(fmaxf(v1.x, v1.y), fmaxf(v1.z, v1.w)));
        m = fmaxf(m, fmaxf(fmaxf(v2.x, v2.y), fmaxf(v2.z, v2.w)));
        m = fmaxf(m, fmaxf(fmaxf(v3.x, v3.y), fmaxf(v3.z, v3.w)));
        m = fmaxf(m, fmaxf(fmaxf(v4.x, v4.y), fmaxf(v4.z, v4.w)));
        m = fmaxf(m, fmaxf(fmaxf(v5.x, v5.y), fmaxf(v5.z, v5.w)));
        m = fmaxf(m, fmaxf(fmaxf(v6.x, v6.y), fmaxf(v6.z, v6.w)));
        m = fmaxf(m, fmaxf(vpro, vtail));

        // Wave-64 max butterfly, then block max via LDS broadcast.
        #pragma unroll
        for (int off = 32; off > 0; off >>= 1) m = fmaxf(m, __shfl_xor(m, off));
        if ((t & 63) == 0) sMax[t >> 6] = m;
        __syncthreads();                                   // barrier A
        const float M = fmaxf(fmaxf(sMax[0], sMax[1]), fmaxf(sMax[2], sMax[3]));

        // ---- Phase B: first index equal to M, scanning held regs high->low ----
        int fi = 0x7fffffff;
        if (vtail == M) fi = tailStart + t;
        {
            const int b6 = pro + 4 * i6;
            if (v6.w == M) fi = b6 + 3;
            if (v6.z == M) fi = b6 + 2;
            if (v6.y == M) fi = b6 + 1;
            if (v6.x == M) fi = b6;
        }
        #define SCAN(v, k)                                   \
            {   const int b = pro + 4 * (t + 256 * (k));     \
                if ((v).w == M) fi = b + 3;                  \
                if ((v).z == M) fi = b + 2;                  \
                if ((v).y == M) fi = b + 1;                  \
                if ((v).x == M) fi = b;                      }
        SCAN(v5, 5) SCAN(v4, 4) SCAN(v3, 3) SCAN(v2, 2) SCAN(v1, 1) SCAN(v0, 0)
        #undef SCAN
        if (vpro == M) fi = t;

        // Wave min butterfly, then block min -> label (first occurrence).
        #pragma unroll
        for (int off = 32; off > 0; off >>= 1) fi = min(fi, __shfl_xor(fi, off));
        if ((t & 63) == 0) sFi[t >> 6] = fi;
        __syncthreads();                                   // barrier B
        const int lab = min(min(sFi[0], sFi[1]), min(sFi[2], sFi[3]));

        // ---- dist via wave 0: lanes 0..23 each hold f, load one float4 of c.
        // NO trailing barrier: waves 1-3 proceed straight into the next row's
        // Phase A loads; wave 0's centers gather overlaps their streaming.
        // LDS safety: next sMax write is after barrier B (program order),
        // next sFi write is after the next barrier A.
        if (t < 64) {
            float sf2 = 0.f, sc2 = 0.f, sfc = 0.f;
            if (t < 24) {   // rows are 384B-aligned
                const float4* c4 = (const float4*)(centers + (size_t)lab * FD);
                float4 c = c4[t];
                sf2 = f.x*f.x + f.y*f.y + f.z*f.z + f.w*f.w;
                sc2 = c.x*c.x + c.y*c.y + c.z*c.z + c.w*c.w;
                sfc = f.x*c.x + f.y*c.y + f.z*c.z + f.w*c.w;
            }
            #pragma unroll
            for (int off = 16; off > 0; off >>= 1) {   // xor<32 stays in 0..31
                sf2 += __shfl_xor(sf2, off);
                sc2 += __shfl_xor(sc2, off);
                sfc += __shfl_xor(sfc, off);
            }
            if (t == 0) {
                float dist = sf2 + sc2 - 2.0f * sfc;
                dist = fminf(fmaxf(dist, 1e-12f), 1e12f);
                row_out[n] = dist;
            }
        }
    }
}

// Deterministic final reduce (single block, fixed order -> bit-identical replays).
__global__ __launch_bounds__(256) void centerloss_reduce_kernel(
    const float* __restrict__ row_out,
    float* __restrict__ out)
{
    const int t = threadIdx.x;
    const float4* r4 = (const float4*)row_out;   // NROW/4 = 1024 float4s
    float s = 0.f;
    #pragma unroll
    for (int k = 0; k < NROW / 4 / 256; ++k) {
        float4 v = r4[t + 256 * k];
        s += v.x + v.y + v.z + v.w;
    }
    #pragma unroll
    for (int off = 32; off > 0; off >>= 1) s += __shfl_xor(s, off);

    __shared__ float sv[4];
    if ((t & 63) == 0) sv[t >> 6] = s;
    __syncthreads();
    if (t == 0)
        out[0] = (sv[0] + sv[1] + sv[2] + sv[3]) / (float)NROW
                 + (float)(NC - 1) * 1e-12f;
}

extern "C" void kernel_launch(void* const* d_in, const int* in_sizes, int n_in,
                              void* d_out, int out_size, void* d_ws, size_t ws_size,
                              hipStream_t stream) {
    const float* features = (const float*)d_in[0];
    const float* predicts = (const float*)d_in[1];
    const float* centers  = (const float*)d_in[2];
    float* out = (float*)d_out;
    float* ws  = (float*)d_ws;   // NROW floats of per-row clipped distances

    centerloss_row_kernel<<<NROW / RPB, 256, 0, stream>>>(features, predicts, centers, ws);
    centerloss_reduce_kernel<<<1, 256, 0, stream>>>(ws, out);
}

// Round 2
// 25.268 us; speedup vs baseline: 1.0520x; 1.0520x over previous
//
#include <hip/hip_runtime.h>

// CenterLoss — R10: decomposition probe of R9's confounded pair.
// Body is EXACTLY R8's (features[n] loaded inside the wave-0 tail — no extended
// live range, no VGPR bloat); the ONLY change vs R8 is removing the trailing
// per-row __syncthreads so waves 1-3 stream row r+1's loads while wave 0
// finishes row r's centers gather + store.
// Barrier safety (2 barriers/row suffice):
//   sMax: row r reads precede barrier B(r); row r+1 writes follow B(r).
//   sFi:  row r reads (incl. wave 0's lab read) precede barrier A(r+1);
//         row r+1 writes follow A(r+1).
// Kept from R5..R8 (measured): 2048 blocks x 2 rows (8 blocks/CU -> all 32
// waves/CU resident in one generation); #pragma unroll 1 (no cross-row load
// hoist); two-kernel store-and-reduce (same-address atomics +45 us, acq-rel
// +165 us — never funnel blocks into one address).
//
// loss = mean_n( clip(||f||^2 + ||c_lab||^2 - 2 f.c_lab, 1e-12, 1e12) ) + (C-1)*1e-12
// lab = argmax_c predicts[n, c]  (first occurrence on ties).

#define NC   6625
#define FD   96
#define NROW 4096
#define RPB  2      // rows per block

__global__ __launch_bounds__(256) void centerloss_row_kernel(
    const float* __restrict__ features,
    const float* __restrict__ predicts,
    const float* __restrict__ centers,
    float* __restrict__ row_out)
{
    const int t = threadIdx.x;
    const float NEG_INF = -__builtin_huge_valf();

    __shared__ float sMax[4];
    __shared__ int   sFi[4];

    #pragma unroll 1
    for (int r = 0; r < RPB; ++r) {
        const int n = blockIdx.x * RPB + r;
        const size_t base = (size_t)n * NC;
        const float* row = predicts + base;

        // Row start is only 4B-aligned (6625 % 4 == 1): scalar prologue to 16B.
        const int pro  = (int)((4 - (base & 3)) & 3);     // 0..3
        const int nvec = (NC - pro) >> 2;                 // 1655 or 1656
        const float4* vrow = (const float4*)(row + pro);

        // ---- Phase A: issue all loads, values live in named registers ----
        // Chunks 0..5 unconditional: max index 255+1280=1535 < min nvec=1655.
        const float4 v0 = vrow[t];
        const float4 v1 = vrow[t +  256];
        const float4 v2 = vrow[t +  512];
        const float4 v3 = vrow[t +  768];
        const float4 v4 = vrow[t + 1024];
        const float4 v5 = vrow[t + 1280];
        float4 v6 = make_float4(NEG_INF, NEG_INF, NEG_INF, NEG_INF);
        const int i6 = t + 1536;
        if (i6 < nvec) v6 = vrow[i6];                     // ~120 lanes valid

        float vpro = NEG_INF;
        if (t < pro) vpro = row[t];                       // idx = t
        const int tailStart = pro + 4 * nvec;
        float vtail = NEG_INF;
        if (t < NC - tailStart) vtail = row[tailStart + t];

        // Thread max via fmax tree (fuses to v_max3_f32); no index tracking.
        float m = fmaxf(fmaxf(fmaxf(v0.x, v0.y), fmaxf(v0.z, v0.w)),
                        fmaxf(fmaxf(v1.x, v1.y), fmaxf(v1.z, v1.w)));
        m = fmaxf(m, fmaxf(fmaxf(v2.x, v2.y), fmaxf(v2.z, v2.w)));
        m = fmaxf(m, fmaxf(fmaxf(v3.x, v3.y), fmaxf(v3.z, v3.w)));
        m = fmaxf(m, fmaxf(fmaxf(v4.x, v4.y), fmaxf(v4.z, v4.w)));
        m = fmaxf(m, fmaxf(fmaxf(v5.x, v5.y), fmaxf(v5.z, v5.w)));
        m = fmaxf(m, fmaxf(fmaxf(v6.x, v6.y), fmaxf(v6.z, v6.w)));
        m = fmaxf(m, fmaxf(vpro, vtail));

        // Wave-64 max butterfly, then block max via LDS broadcast.
        #pragma unroll
        for (int off = 32; off > 0; off >>= 1) m = fmaxf(m, __shfl_xor(m, off));
        if ((t & 63) == 0) sMax[t >> 6] = m;
        __syncthreads();                                   // barrier A
        const float M = fmaxf(fmaxf(sMax[0], sMax[1]), fmaxf(sMax[2], sMax[3]));

        // ---- Phase B: first index equal to M, scanning held regs high->low ----
        int fi = 0x7fffffff;
        if (vtail == M) fi = tailStart + t;
        {
            const int b6 = pro + 4 * i6;
            if (v6.w == M) fi = b6 + 3;
            if (v6.z == M) fi = b6 + 2;
            if (v6.y == M) fi = b6 + 1;
            if (v6.x == M) fi = b6;
        }
        #define SCAN(v, k)                                   \
            {   const int b = pro + 4 * (t + 256 * (k));     \
                if ((v).w == M) fi = b + 3;                  \
                if ((v).z == M) fi = b + 2;                  \
                if ((v).y == M) fi = b + 1;                  \
                if ((v).x == M) fi = b;                      }
        SCAN(v5, 5) SCAN(v4, 4) SCAN(v3, 3) SCAN(v2, 2) SCAN(v1, 1) SCAN(v0, 0)
        #undef SCAN
        if (vpro == M) fi = t;

        // Wave min butterfly, then block min -> label (first occurrence).
        #pragma unroll
        for (int off = 32; off > 0; off >>= 1) fi = min(fi, __shfl_xor(fi, off));
        if ((t & 63) == 0) sFi[t >> 6] = fi;
        __syncthreads();                                   // barrier B
        const int lab = min(min(sFi[0], sFi[1]), min(sFi[2], sFi[3]));

        // ---- dist via wave 0: lanes 0..23 each load one float4 of f and c ----
        // f and c loads issue back-to-back (f needs no lab) -> latencies overlap.
        // NO trailing barrier: waves 1-3 proceed into row r+1's Phase A loads
        // while wave 0 gathers + stores (safety proof in header).
        if (t < 64) {
            float sf2 = 0.f, sc2 = 0.f, sfc = 0.f;
            if (t < 24) {   // 24 * float4 = 96 floats; rows are 384B-aligned
                const float4* f4 = (const float4*)(features + (size_t)n   * FD);
                const float4* c4 = (const float4*)(centers  + (size_t)lab * FD);
                float4 f = f4[t], c = c4[t];
                sf2 = f.x*f.x + f.y*f.y + f.z*f.z + f.w*f.w;
                sc2 = c.x*c.x + c.y*c.y + c.z*c.z + c.w*c.w;
                sfc = f.x*c.x + f.y*c.y + f.z*c.z + f.w*c.w;
            }
            #pragma unroll
            for (int off = 16; off > 0; off >>= 1) {   // xor<32 stays in 0..31
                sf2 += __shfl_xor(sf2, off);
                sc2 += __shfl_xor(sc2, off);
                sfc += __shfl_xor(sfc, off);
            }
            if (t == 0) {
                float dist = sf2 + sc2 - 2.0f * sfc;
                dist = fminf(fmaxf(dist, 1e-12f), 1e12f);
                row_out[n] = dist;
            }
        }
    }
}

// Deterministic final reduce (single block, fixed order -> bit-identical replays).
__global__ __launch_bounds__(256) void centerloss_reduce_kernel(
    const float* __restrict__ row_out,
    float* __restrict__ out)
{
    const int t = threadIdx.x;
    const float4* r4 = (const float4*)row_out;   // NROW/4 = 1024 float4s
    float s = 0.f;
    #pragma unroll
    for (int k = 0; k < NROW / 4 / 256; ++k) {
        float4 v = r4[t + 256 * k];
        s += v.x + v.y + v.z + v.w;
    }
    #pragma unroll
    for (int off = 32; off > 0; off >>= 1) s += __shfl_xor(s, off);

    __shared__ float sv[4];
    if ((t & 63) == 0) sv[t >> 6] = s;
    __syncthreads();
    if (t == 0)
        out[0] = (sv[0] + sv[1] + sv[2] + sv[3]) / (float)NROW
                 + (float)(NC - 1) * 1e-12f;
}

extern "C" void kernel_launch(void* const* d_in, const int* in_sizes, int n_in,
                              void* d_out, int out_size, void* d_ws, size_t ws_size,
                              hipStream_t stream) {
    const float* features = (const float*)d_in[0];
    const float* predicts = (const float*)d_in[1];
    const float* centers  = (const float*)d_in[2];
    float* out = (float*)d_out;
    float* ws  = (float*)d_ws;   // NROW floats of per-row clipped distances

    centerloss_row_kernel<<<NROW / RPB, 256, 0, stream>>>(features, predicts, centers, ws);
    centerloss_reduce_kernel<<<1, 256, 0, stream>>>(ws, out);
}